// Round 1
// baseline (75.880 us; speedup 1.0000x reference)
//
#include <hip/hip_runtime.h>

#define BATCH 2048
#define NCLS  1000
#define FEAT  128

typedef short bf16x8 __attribute__((ext_vector_type(8)));
typedef float f32x16 __attribute__((ext_vector_type(16)));

// RNE float->bf16, identical to the validated prep-kernel conversion, so the
// MFMA inputs (and therefore logits) are bit-identical to the passing kernel.
__device__ __forceinline__ unsigned int f2bf(float f) {
    unsigned int u;
    __builtin_memcpy(&u, &f, 4);
    return (u + 0x7fffu + ((u >> 16) & 1u)) >> 16;
}

// Load 8 consecutive fp32, accumulate |x|^2 partial in fp32, emit bf16x8.
__device__ __forceinline__ bf16x8 cvt_chunk(const float* __restrict__ p, float& nrm) {
    float4 lo = *(const float4*)p;
    float4 hi = *(const float4*)(p + 4);
    nrm += lo.x * lo.x + lo.y * lo.y + lo.z * lo.z + lo.w * lo.w +
           hi.x * hi.x + hi.y * hi.y + hi.z * hi.z + hi.w * hi.w;
    bf16x8 r;
    r[0] = (short)f2bf(lo.x); r[1] = (short)f2bf(lo.y);
    r[2] = (short)f2bf(lo.z); r[3] = (short)f2bf(lo.w);
    r[4] = (short)f2bf(hi.x); r[5] = (short)f2bf(hi.y);
    r[6] = (short)f2bf(hi.z); r[7] = (short)f2bf(hi.w);
    return r;
}

// Single fused kernel: 512 blocks (32 row-tiles x 16 col-tiles), 256 threads =
// 4 waves in a 2x2 grid of 32x32 MFMA tiles (64x64 block tile).
// Per lane: load its A-row / B-row fragments as fp32 directly from global
// (L2-resident), convert to bf16 in-register, MFMA over K=128, and compute
// the fp32 row/col norms as a side product of the same loads.
// Likelihood comes from the matched diagonal dist (c0 == label[row]):
// per-block partial -> ws[blockIdx.x], reduced by the trailing 1-block kernel.
__global__ __launch_bounds__(256) void lgm_fused(
    const float* __restrict__ feat,
    const float* __restrict__ centers,
    const int* __restrict__ label,
    float* __restrict__ ws,
    float* __restrict__ out)
{
    __shared__ float fn_lds[64];   // |feat row|^2 for this block's 64 rows
    __shared__ float red[4];

    int tid     = threadIdx.x;
    int lane    = tid & 63;
    int wave    = tid >> 6;                 // 0..3
    int tileCol = blockIdx.x & 15;
    int tileRow = blockIdx.x >> 4;
    int rowBase = tileRow * 64 + (wave & 1) * 32;
    int colBase = tileCol * 64 + (wave >> 1) * 32;
    int m       = lane & 31;
    int half    = lane >> 5;                // 0..1

    int r  = rowBase + m;                   // A row for this lane
    int c0 = colBase + m;                   // output col for this lane
    int c  = (c0 < NCLS) ? c0 : (NCLS - 1); // clamped for loads

    const float* ap = feat    + r * FEAT + half * 8;
    const float* bp = centers + c * FEAT + half * 8;

    float fs = 0.0f, cs = 0.0f;             // half-row norm partials (fp32)
    f32x16 acc = {};
    #pragma unroll
    for (int kk = 0; kk < 8; kk++) {        // K=128 in steps of 16
        bf16x8 a = cvt_chunk(ap + kk * 16, fs); // A[m][k=half*8+kk*16+j]
        bf16x8 b = cvt_chunk(bp + kk * 16, cs); // B^T[n][k]
        acc = __builtin_amdgcn_mfma_f32_32x32x16_bf16(a, b, acc, 0, 0, 0);
    }

    // Combine the two half-row partials: lanes m and m+32 both end up with the
    // full norm of their (row r / col c).
    fs += __shfl_xor(fs, 32, 64);
    cs += __shfl_xor(cs, 32, 64);
    fn_lds[(wave & 1) * 32 + m] = fs;       // waves 0/2 (and 1/3) dup-write same value
    __syncthreads();

    // C/D mapping (m74/m101): col = lane&31, row = (reg&3) + 8*(reg>>2) + 4*half
    float* out0 = out;                      // logits        [2048,1000]
    float* out1 = out + BATCH * NCLS;       // margin_logits [2048,1000]
    float cnv   = cs;                       // |center c|^2
    bool  colOK = (c0 < NCLS);
    int   rlb   = (wave & 1) * 32;
    float lsum  = 0.0f;
    #pragma unroll
    for (int reg = 0; reg < 16; reg++) {
        int rl  = rlb + (reg & 3) + 8 * (reg >> 2) + 4 * half;
        int row = tileRow * 64 + rl;
        if (colOK) {
            float dist  = fn_lds[rl] + cnv - 2.0f * acc[reg];
            float logit = -0.5f * dist;
            int   idx   = row * NCLS + c0;
            bool  match = (c0 == label[row]);
            out0[idx] = logit;
            out1[idx] = match ? 2.0f * logit : logit;
            if (match) lsum += dist;        // diagonal term for likelihood
        }
    }

    // Block-reduce the likelihood partial -> ws[blockIdx.x] (no atomics, no init).
    #pragma unroll
    for (int off = 32; off > 0; off >>= 1) lsum += __shfl_down(lsum, off, 64);
    if (lane == 0) red[wave] = lsum;
    __syncthreads();
    if (tid == 0) ws[blockIdx.x] = red[0] + red[1] + red[2] + red[3];
}

// Reduce the 512 per-block partials (exactly 8 per lane) into the scalar.
__global__ __launch_bounds__(64) void lgm_finish(
    const float* __restrict__ ws,
    float* __restrict__ out)
{
    int lane = threadIdx.x;
    float s = 0.0f;
    #pragma unroll
    for (int j = 0; j < 8; j++) s += ws[lane + 64 * j];
    #pragma unroll
    for (int off = 32; off > 0; off >>= 1) s += __shfl_down(s, off, 64);
    if (lane == 0) out[2 * BATCH * NCLS] = s * (0.5f / (float)BATCH);
}

extern "C" void kernel_launch(void* const* d_in, const int* in_sizes, int n_in,
                              void* d_out, int out_size, void* d_ws, size_t ws_size,
                              hipStream_t stream) {
    const float* feat    = (const float*)d_in[0];
    const int*   label   = (const int*)d_in[1];
    const float* centers = (const float*)d_in[2];
    float* ws = (float*)d_ws;

    lgm_fused<<<512, 256, 0, stream>>>(feat, centers, label, ws, (float*)d_out);
    lgm_finish<<<1, 64, 0, stream>>>(ws, (float*)d_out);
}

// Round 2
// 74.186 us; speedup vs baseline: 1.0228x; 1.0228x over previous
//
#include <hip/hip_runtime.h>

#define BATCH 2048
#define NCLS  1000
#define FEAT  128

typedef short bf16x8 __attribute__((ext_vector_type(8)));
typedef float f32x4  __attribute__((ext_vector_type(4)));

// ws float-word layout:
//   [0      .. 512)     likelihood block partials (one per prep feat-block)
//   [512    .. 2560)    fn[b] = |feat_b|^2
//   [2560   .. 3560)    cn[c] = |center_c|^2
//   [4096   .. 135168)  feat bf16 copy    (2048*128 bf16, packed 2/word)
//   [135168 .. 199168)  centers bf16 copy (1000*128 bf16, packed 2/word)
#define WS_LP   0
#define WS_FN   512
#define WS_CN   2560
#define WS_FB   4096
#define WS_CB   135168

__device__ inline unsigned int f2bf(float f) {
    unsigned int u;
    __builtin_memcpy(&u, &f, 4);
    return (u + 0x7fffu + ((u >> 16) & 1u)) >> 16;   // RNE
}

// One wave per row: w in [0,2048) = feat rows (|f|^2, likelihood partial, bf16
// copy), w in [2048,3048) = center rows (|c|^2, bf16 copy). Blocks 0..511 are
// pure feat blocks; each writes ONE likelihood partial (no atomics).
__global__ __launch_bounds__(256) void prep_kernel(
    const float* __restrict__ feat,
    const float* __restrict__ centers,
    const int* __restrict__ label,
    float* __restrict__ ws)
{
    __shared__ float lp[4];
    int w    = blockIdx.x * 4 + (threadIdx.x >> 6);
    int lane = threadIdx.x & 63;
    float* fn = ws + WS_FN;
    float* cn = ws + WS_CN;
    unsigned int* fb = (unsigned int*)(ws + WS_FB);
    unsigned int* cb = (unsigned int*)(ws + WS_CB);

    if (w < BATCH) {
        int b = w;
        float2 f = *(const float2*)(feat + b * FEAT + lane * 2);
        int lb = label[b];
        float2 c = *(const float2*)(centers + lb * FEAT + lane * 2);
        fb[b * 64 + lane] = f2bf(f.x) | (f2bf(f.y) << 16);
        float fs = f.x * f.x + f.y * f.y;
        float d0 = f.x - c.x, d1 = f.y - c.y;
        float ls = d0 * d0 + d1 * d1;
        #pragma unroll
        for (int off = 32; off > 0; off >>= 1) {
            fs += __shfl_down(fs, off, 64);
            ls += __shfl_down(ls, off, 64);
        }
        if (lane == 0) {
            fn[b] = fs;
            lp[threadIdx.x >> 6] = ls;
        }
    } else if (w < BATCH + NCLS) {
        int c = w - BATCH;
        float2 cv = *(const float2*)(centers + c * FEAT + lane * 2);
        cb[c * 64 + lane] = f2bf(cv.x) | (f2bf(cv.y) << 16);
        float cs = cv.x * cv.x + cv.y * cv.y;
        #pragma unroll
        for (int off = 32; off > 0; off >>= 1) cs += __shfl_down(cs, off, 64);
        if (lane == 0) cn[c] = cs;
    }

    if (blockIdx.x < 512) {            // block-uniform branch
        __syncthreads();
        if (threadIdx.x == 0)
            ws[WS_LP + blockIdx.x] = lp[0] + lp[1] + lp[2] + lp[3];
    }
}

// 16x16 output tile per wave, K=128 via 4 x mfma_f32_16x16x32_bf16.
// 8192 tiles (128 row-tiles x 64 padded col-tiles) / 4 waves per block
// = 2048 blocks -> 8 blocks/CU, 32 waves/CU (full occupancy) for latency
// hiding of the pure bf16x8 L2 loads.
// A-frag: row = lane&15, k = (lane>>4)*8 + j (8 contiguous bf16).
// C/D (m89/m91): col = lane&15, row = (lane>>4)*4 + reg.
// Block 0 additionally reduces the 512 likelihood partials.
__global__ __launch_bounds__(256) void lgm_main_kernel(
    const int* __restrict__ label,
    const float* __restrict__ ws,
    float* __restrict__ out)
{
    const float* fn = ws + WS_FN;
    const float* cn = ws + WS_CN;
    const unsigned short* fb = (const unsigned short*)(ws + WS_FB);
    const unsigned short* cb = (const unsigned short*)(ws + WS_CB);

    int tid  = threadIdx.x;
    int lane = tid & 63;
    int wave = tid >> 6;                    // 0..3
    int t    = blockIdx.x * 4 + wave;       // tile id, 0..8191
    int tileCol = t & 63;                   // 64 col-tiles (cols padded to 1024)
    int tileRow = t >> 6;                   // 128 row-tiles
    int sub  = lane & 15;
    int kq   = lane >> 4;                   // 0..3

    int row = tileRow * 16 + sub;           // A row for this lane
    int c0  = tileCol * 16 + sub;           // output col for this lane
    int c   = (c0 < NCLS) ? c0 : (NCLS - 1); // clamped for loads

    const unsigned short* ap = fb + row * FEAT + kq * 8;
    const unsigned short* bp = cb + c   * FEAT + kq * 8;

    f32x4 acc = {};
    #pragma unroll
    for (int kk = 0; kk < 4; kk++) {        // K=128 in steps of 32
        bf16x8 a = *(const bf16x8*)(ap + kk * 32);
        bf16x8 b = *(const bf16x8*)(bp + kk * 32);
        acc = __builtin_amdgcn_mfma_f32_16x16x32_bf16(a, b, acc, 0, 0, 0);
    }

    float* out0 = out;                      // logits        [2048,1000]
    float* out1 = out + BATCH * NCLS;       // margin_logits [2048,1000]
    float cnv   = cn[c];
    bool  colOK = (c0 < NCLS);
    #pragma unroll
    for (int reg = 0; reg < 4; reg++) {
        int orow = tileRow * 16 + kq * 4 + reg;
        if (colOK) {
            float dist  = fn[orow] + cnv - 2.0f * acc[reg];
            float logit = -0.5f * dist;
            int   idx   = orow * NCLS + c0;
            out0[idx] = logit;
            out1[idx] = (c0 == label[orow]) ? 2.0f * logit : logit;
        }
    }

    // Likelihood: sum the 512 prep partials (exactly 8 per lane), one wave.
    if (blockIdx.x == 0 && tid < 64) {
        float s = 0.0f;
        #pragma unroll
        for (int j = 0; j < 8; j++) s += ws[WS_LP + lane + 64 * j];
        #pragma unroll
        for (int off = 32; off > 0; off >>= 1) s += __shfl_down(s, off, 64);
        if (lane == 0) out[2 * BATCH * NCLS] = s * (0.5f / (float)BATCH);
    }
}

extern "C" void kernel_launch(void* const* d_in, const int* in_sizes, int n_in,
                              void* d_out, int out_size, void* d_ws, size_t ws_size,
                              hipStream_t stream) {
    const float* feat    = (const float*)d_in[0];
    const int*   label   = (const int*)d_in[1];
    const float* centers = (const float*)d_in[2];
    float* ws = (float*)d_ws;

    prep_kernel<<<762, 256, 0, stream>>>(feat, centers, label, ws);
    lgm_main_kernel<<<2048, 256, 0, stream>>>(label, ws, (float*)d_out);
}

// Round 3
// 72.995 us; speedup vs baseline: 1.0395x; 1.0163x over previous
//
#include <hip/hip_runtime.h>

#define BATCH 2048
#define NCLS  1000
#define FEAT  128

typedef short bf16x8 __attribute__((ext_vector_type(8)));
typedef float f32x16 __attribute__((ext_vector_type(16)));

// ws float-word layout:
//   [0      .. 512)     likelihood block partials (one per prep feat-block)
//   [512    .. 2560)    fn[b] = |feat_b|^2
//   [2560   .. 3560)    cn[c] = |center_c|^2
//   [4096   .. 135168)  feat bf16 copy    (2048*128 bf16, packed 2/word)
//   [135168 .. 199168)  centers bf16 copy (1000*128 bf16, packed 2/word)
#define WS_LP   0
#define WS_FN   512
#define WS_CN   2560
#define WS_FB   4096
#define WS_CB   135168

__device__ inline unsigned int f2bf(float f) {
    unsigned int u;
    __builtin_memcpy(&u, &f, 4);
    return (u + 0x7fffu + ((u >> 16) & 1u)) >> 16;   // RNE
}

// One wave per row: w in [0,2048) = feat rows (|f|^2, likelihood partial, bf16
// copy), w in [2048,3048) = center rows (|c|^2, bf16 copy). Blocks 0..511 are
// pure feat blocks; each writes ONE likelihood partial (no atomics).
__global__ __launch_bounds__(256) void prep_kernel(
    const float* __restrict__ feat,
    const float* __restrict__ centers,
    const int* __restrict__ label,
    float* __restrict__ ws)
{
    __shared__ float lp[4];
    int w    = blockIdx.x * 4 + (threadIdx.x >> 6);
    int lane = threadIdx.x & 63;
    float* fn = ws + WS_FN;
    float* cn = ws + WS_CN;
    unsigned int* fb = (unsigned int*)(ws + WS_FB);
    unsigned int* cb = (unsigned int*)(ws + WS_CB);

    if (w < BATCH) {
        int b = w;
        float2 f = *(const float2*)(feat + b * FEAT + lane * 2);
        int lb = label[b];
        float2 c = *(const float2*)(centers + lb * FEAT + lane * 2);
        fb[b * 64 + lane] = f2bf(f.x) | (f2bf(f.y) << 16);
        float fs = f.x * f.x + f.y * f.y;
        float d0 = f.x - c.x, d1 = f.y - c.y;
        float ls = d0 * d0 + d1 * d1;
        #pragma unroll
        for (int off = 32; off > 0; off >>= 1) {
            fs += __shfl_down(fs, off, 64);
            ls += __shfl_down(ls, off, 64);
        }
        if (lane == 0) {
            fn[b] = fs;
            lp[threadIdx.x >> 6] = ls;
        }
    } else if (w < BATCH + NCLS) {
        int c = w - BATCH;
        float2 cv = *(const float2*)(centers + c * FEAT + lane * 2);
        cb[c * 64 + lane] = f2bf(cv.x) | (f2bf(cv.y) << 16);
        float cs = cv.x * cv.x + cv.y * cv.y;
        #pragma unroll
        for (int off = 32; off > 0; off >>= 1) cs += __shfl_down(cs, off, 64);
        if (lane == 0) cn[c] = cs;
    }

    if (blockIdx.x < 512) {            // block-uniform branch
        __syncthreads();
        if (threadIdx.x == 0)
            ws[WS_LP + blockIdx.x] = lp[0] + lp[1] + lp[2] + lp[3];
    }
}

// 256 threads = 4 waves in a 2x2 grid of 32x32 tiles -> 64x64 block tile.
// OPERANDS SWAPPED vs the 71.6us baseline: A = centers, B = feat, so the
// C/D mapping (col=lane&31, row=(reg&3)+8*(reg>>2)+4*half — m74/m101) puts
// one FEAT ROW per lane and 16 CENTER COLS in the regs, in 4 groups of 4
// consecutive cols. Epilogue: 1 fn load + 1 label load + 4 cn float4 loads
// + 8 float4 stores per lane (was 16+16+1 scalar loads and 32 dword stores).
// Col-bounds check is per-group uniform (NCLS=1000 is a multiple of 4).
__global__ __launch_bounds__(256) void lgm_main_kernel(
    const int* __restrict__ label,
    const float* __restrict__ ws,
    float* __restrict__ out)
{
    const float* fn = ws + WS_FN;
    const float* cn = ws + WS_CN;
    const unsigned short* fb = (const unsigned short*)(ws + WS_FB);
    const unsigned short* cb = (const unsigned short*)(ws + WS_CB);

    int tid     = threadIdx.x;
    int lane    = tid & 63;
    int wave    = tid >> 6;                 // 0..3
    int tileCol = blockIdx.x & 15;          // over centers (padded to 1024)
    int tileRow = blockIdx.x >> 4;          // over feat rows
    int nBase   = tileRow * 64 + (wave & 1) * 32;   // feat-row base (N side)
    int mBase   = tileCol * 64 + (wave >> 1) * 32;  // center base  (M side)
    int m       = lane & 31;
    int half    = lane >> 5;                // 0..1

    int r  = nBase + m;                         // this lane's feat row (B op)
    int cA = mBase + m;                         // this lane's center row (A op)
    int cAc = (cA < NCLS) ? cA : (NCLS - 1);    // clamped for loads

    const unsigned short* ap = cb + cAc * FEAT + half * 8;  // A = centers
    const unsigned short* bp = fb + r   * FEAT + half * 8;  // B = feat

    // Prefetch epilogue operands before the MFMA chain.
    float fnv = fn[r];
    int   lb  = label[r];

    f32x16 acc = {};
    #pragma unroll
    for (int kk = 0; kk < 8; kk++) {        // K=128 in steps of 16
        bf16x8 a = *(const bf16x8*)(ap + kk * 16);
        bf16x8 b = *(const bf16x8*)(bp + kk * 16);
        acc = __builtin_amdgcn_mfma_f32_32x32x16_bf16(a, b, acc, 0, 0, 0);
    }

    // D[center c][feat row r]: col = lane&31 -> feat row r (all valid),
    // row = (reg&3) + 8*(reg>>2) + 4*half -> center col offset from mBase.
    float* out0 = out;                      // logits        [2048,1000]
    float* out1 = out + BATCH * NCLS;       // margin_logits [2048,1000]
    #pragma unroll
    for (int g = 0; g < 4; g++) {           // reg>>2 groups: 4 consecutive cols
        int ccol = mBase + g * 8 + 4 * half;
        if (ccol < NCLS) {                  // group fully valid or fully out
            float4 cnv = *(const float4*)(cn + ccol);
            float4 lg, mg;
            float d0 = fnv + cnv.x - 2.0f * acc[g * 4 + 0];
            float d1 = fnv + cnv.y - 2.0f * acc[g * 4 + 1];
            float d2 = fnv + cnv.z - 2.0f * acc[g * 4 + 2];
            float d3 = fnv + cnv.w - 2.0f * acc[g * 4 + 3];
            lg.x = -0.5f * d0; lg.y = -0.5f * d1;
            lg.z = -0.5f * d2; lg.w = -0.5f * d3;
            mg.x = (ccol + 0 == lb) ? 2.0f * lg.x : lg.x;
            mg.y = (ccol + 1 == lb) ? 2.0f * lg.y : lg.y;
            mg.z = (ccol + 2 == lb) ? 2.0f * lg.z : lg.z;
            mg.w = (ccol + 3 == lb) ? 2.0f * lg.w : lg.w;
            int idx = r * NCLS + ccol;
            *(float4*)(out0 + idx) = lg;
            *(float4*)(out1 + idx) = mg;
        }
    }

    // Likelihood: sum the 512 prep partials (exactly 8 per lane), one wave.
    if (blockIdx.x == 0 && tid < 64) {
        float s = 0.0f;
        #pragma unroll
        for (int j = 0; j < 8; j++) s += ws[WS_LP + lane + 64 * j];
        #pragma unroll
        for (int off = 32; off > 0; off >>= 1) s += __shfl_down(s, off, 64);
        if (lane == 0) out[2 * BATCH * NCLS] = s * (0.5f / (float)BATCH);
    }
}

extern "C" void kernel_launch(void* const* d_in, const int* in_sizes, int n_in,
                              void* d_out, int out_size, void* d_ws, size_t ws_size,
                              hipStream_t stream) {
    const float* feat    = (const float*)d_in[0];
    const int*   label   = (const int*)d_in[1];
    const float* centers = (const float*)d_in[2];
    float* ws = (float*)d_ws;

    prep_kernel<<<762, 256, 0, stream>>>(feat, centers, label, ws);
    lgm_main_kernel<<<512, 256, 0, stream>>>(label, ws, (float*)d_out);
}

// Round 4
// 71.651 us; speedup vs baseline: 1.0590x; 1.0188x over previous
//
#include <hip/hip_runtime.h>

#define BATCH 2048
#define NCLS  1000
#define FEAT  128

typedef short bf16x8 __attribute__((ext_vector_type(8)));
typedef float f32x16 __attribute__((ext_vector_type(16)));

// ws float-word layout: [0..32) likelihood partials, one per tileCol==0 block.
#define WS_LP 0

__device__ inline unsigned int f2bf(float f) {
    unsigned int u;
    __builtin_memcpy(&u, &f, 4);
    return (u + 0x7fffu + ((u >> 16) & 1u)) >> 16;   // RNE
}

// Single main kernel: 512 blocks (32 row-tiles x 16 col-tiles of 64x64),
// 256 threads = 4 waves in a 2x2 grid of 32x32 MFMA tiles.
//
// Staging phase (replaces the old prep kernel + its drain boundary): each
// block loads its 64 feat rows + 64 center rows fp32 from L2, converts to
// bf16 into LDS ONCE (amortized across the block's 4 waves), computing the
// fp32 row norms as a side product. LDS tiles are [64][128] bf16 with the
// verified XOR swizzle byte^=((row&7)<<4) — row-major D=128 would otherwise
// be a 32-way bank conflict on ds_read_b128 (guide G4).
//
// Likelihood is fp32-EXACT as in the 71.6us baseline: the 32 tileCol==0
// blocks load centers[label[r]] fp32 during feat staging and accumulate
// sum((f-c)^2) -> ws[tileRow]; the trailing 1-block kernel reduces 32 values.
//
// MFMA phase + epilogue are verbatim the measured-best round-0 structure:
// A = feat, B^T = centers, mfma_f32_32x32x16_bf16 x8 over K=128,
// C/D mapping (m74/m101): col = lane&31, row = (reg&3)+8*(reg>>2)+4*half.
__global__ __launch_bounds__(256) void lgm_main_kernel(
    const float* __restrict__ feat,
    const float* __restrict__ centers,
    const int* __restrict__ label,
    float* __restrict__ ws,
    float* __restrict__ out)
{
    __shared__ __align__(16) unsigned char smem[33296];
    unsigned char* sA  = smem;                    // feat tile: 64 x 256B bf16, swizzled
    unsigned char* sB  = smem + 16384;            // centers tile: 64 x 256B bf16, swizzled
    float*         sFn = (float*)(smem + 32768);  // 64 feat-row norms
    float*         sCn = (float*)(smem + 33024);  // 64 center norms
    float*         red = (float*)(smem + 33280);  // 4 likelihood wave-partials

    int tid     = threadIdx.x;
    int lane    = tid & 63;
    int wave    = tid >> 6;                 // 0..3
    int tileCol = blockIdx.x & 15;
    int tileRow = blockIdx.x >> 4;
    int fr0     = tileRow * 64;             // global feat-row base
    int cr0     = tileCol * 64;             // global center base (padded to 1024)

    // ---------------- staging: 4 threads per row, 32 floats each ----------
    int srow = tid >> 2;                    // 0..63 (block-local row)
    int sq   = tid & 3;                     // 32-float chunk within the row

    {   // feat rows -> sA, |f|^2 -> sFn, (tileCol==0) likelihood partial
        const float* src = feat + (fr0 + srow) * FEAT + sq * 32;
        float v[32];
        #pragma unroll
        for (int j = 0; j < 8; j++) {
            float4 t = ((const float4*)src)[j];
            v[4*j+0] = t.x; v[4*j+1] = t.y; v[4*j+2] = t.z; v[4*j+3] = t.w;
        }
        float ns = 0.0f;
        unsigned int w[16];
        #pragma unroll
        for (int i = 0; i < 16; i++) {
            ns  += v[2*i] * v[2*i] + v[2*i+1] * v[2*i+1];
            w[i] = f2bf(v[2*i]) | (f2bf(v[2*i+1]) << 16);
        }
        #pragma unroll
        for (int s = 0; s < 4; s++) {
            int off = sq * 64 + s * 16;
            int swz = off ^ ((srow & 7) << 4);
            uint4 t4; t4.x = w[4*s]; t4.y = w[4*s+1]; t4.z = w[4*s+2]; t4.w = w[4*s+3];
            *(uint4*)(sA + srow * 256 + swz) = t4;
        }
        ns += __shfl_xor(ns, 1, 64);
        ns += __shfl_xor(ns, 2, 64);
        if (sq == 0) sFn[srow] = ns;

        if (tileCol == 0) {                 // fp32-exact likelihood partial
            int lb = label[fr0 + srow];
            const float* cl = centers + lb * FEAT + sq * 32;
            float lsq = 0.0f;
            #pragma unroll
            for (int j = 0; j < 8; j++) {
                float4 t = ((const float4*)cl)[j];
                float d0 = v[4*j+0] - t.x, d1 = v[4*j+1] - t.y;
                float d2 = v[4*j+2] - t.z, d3 = v[4*j+3] - t.w;
                lsq += d0*d0 + d1*d1 + d2*d2 + d3*d3;
            }
            #pragma unroll
            for (int off = 32; off > 0; off >>= 1) lsq += __shfl_down(lsq, off, 64);
            if (lane == 0) red[wave] = lsq; // wave covers exactly rows wave*16..+16
        }
    }

    {   // center rows -> sB, |c|^2 -> sCn (clamped for padded cols >= NCLS)
        int cr  = cr0 + srow;
        int crc = (cr < NCLS) ? cr : (NCLS - 1);
        const float* src = centers + crc * FEAT + sq * 32;
        float v[32];
        #pragma unroll
        for (int j = 0; j < 8; j++) {
            float4 t = ((const float4*)src)[j];
            v[4*j+0] = t.x; v[4*j+1] = t.y; v[4*j+2] = t.z; v[4*j+3] = t.w;
        }
        float ns = 0.0f;
        unsigned int w[16];
        #pragma unroll
        for (int i = 0; i < 16; i++) {
            ns  += v[2*i] * v[2*i] + v[2*i+1] * v[2*i+1];
            w[i] = f2bf(v[2*i]) | (f2bf(v[2*i+1]) << 16);
        }
        #pragma unroll
        for (int s = 0; s < 4; s++) {
            int off = sq * 64 + s * 16;
            int swz = off ^ ((srow & 7) << 4);
            uint4 t4; t4.x = w[4*s]; t4.y = w[4*s+1]; t4.z = w[4*s+2]; t4.w = w[4*s+3];
            *(uint4*)(sB + srow * 256 + swz) = t4;
        }
        ns += __shfl_xor(ns, 1, 64);
        ns += __shfl_xor(ns, 2, 64);
        if (sq == 0) sCn[srow] = ns;
    }

    __syncthreads();

    if (tileCol == 0 && tid == 0)
        ws[WS_LP + tileRow] = red[0] + red[1] + red[2] + red[3];

    // ---------------- MFMA: 8 x mfma_f32_32x32x16_bf16 over K=128 ----------
    int m    = lane & 31;
    int half = lane >> 5;                   // 0..1
    int rl   = (wave & 1) * 32 + m;         // block-local feat row (A)
    int cl_  = (wave >> 1) * 32 + m;        // block-local center row (B^T)
    int rsw  = (rl  & 7) << 4;
    int csw  = (cl_ & 7) << 4;

    f32x16 acc = {};
    #pragma unroll
    for (int kk = 0; kk < 8; kk++) {        // K=128 in steps of 16
        int off = half * 16 + kk * 32;      // byte offset of 8 bf16 at k=half*8+kk*16
        bf16x8 a = *(const bf16x8*)(sA + rl  * 256 + (off ^ rsw));
        bf16x8 b = *(const bf16x8*)(sB + cl_ * 256 + (off ^ csw));
        acc = __builtin_amdgcn_mfma_f32_32x32x16_bf16(a, b, acc, 0, 0, 0);
    }

    // ---------------- epilogue (round-0 verbatim, norms from LDS) ----------
    float* out0 = out;                      // logits        [2048,1000]
    float* out1 = out + BATCH * NCLS;       // margin_logits [2048,1000]
    int   c0    = cr0 + (wave >> 1) * 32 + m;
    float cnv   = sCn[(wave >> 1) * 32 + m];
    bool  colOK = (c0 < NCLS);
    #pragma unroll
    for (int reg = 0; reg < 16; reg++) {
        int rloc = (wave & 1) * 32 + (reg & 3) + 8 * (reg >> 2) + 4 * half;
        int row  = fr0 + rloc;
        if (colOK) {
            float dist  = sFn[rloc] + cnv - 2.0f * acc[reg];
            float logit = -0.5f * dist;
            int   idx   = row * NCLS + c0;
            out0[idx] = logit;
            out1[idx] = (c0 == label[row]) ? 2.0f * logit : logit;
        }
    }
}

// Reduce the 32 per-row-tile likelihood partials into the scalar.
__global__ __launch_bounds__(64) void lgm_finish(
    const float* __restrict__ ws,
    float* __restrict__ out)
{
    int lane = threadIdx.x;
    float s = (lane < 32) ? ws[WS_LP + lane] : 0.0f;
    #pragma unroll
    for (int off = 32; off > 0; off >>= 1) s += __shfl_down(s, off, 64);
    if (lane == 0) out[2 * BATCH * NCLS] = s * (0.5f / (float)BATCH);
}

extern "C" void kernel_launch(void* const* d_in, const int* in_sizes, int n_in,
                              void* d_out, int out_size, void* d_ws, size_t ws_size,
                              hipStream_t stream) {
    const float* feat    = (const float*)d_in[0];
    const int*   label   = (const int*)d_in[1];
    const float* centers = (const float*)d_in[2];
    float* ws = (float*)d_ws;

    lgm_main_kernel<<<512, 256, 0, stream>>>(feat, centers, label, ws, (float*)d_out);
    lgm_finish<<<1, 64, 0, stream>>>(ws, (float*)d_out);
}